// Round 4
// baseline (534.735 us; speedup 1.0000x reference)
//
#include <hip/hip_runtime.h>

// Problem constants (fixed by reference setup_inputs)
constexpr int B  = 4;
constexpr int C  = 128;    // == Cv
constexpr int hw = 16384;  // h*w = 128*128
constexpr int W_ = 256;
constexpr int HW = 65536;  // H*W
constexpr int K  = 16;
constexpr int P_TILE = 16;                       // positions per block
constexpr int BLOCKS_PER_BATCH = hw / P_TILE;    // 1024

// (C, N) fp32 -> (N, C) fp32, one batch per blockIdx.z
__global__ __launch_bounds__(256) void transpose_f32(
    const float* __restrict__ src, float* __restrict__ dst, int N)
{
    __shared__ float tile[64][65];
    const int bz = blockIdx.z;
    const int n0 = blockIdx.x * 64;
    const int c0 = blockIdx.y * 64;
    const int tx = threadIdx.x;   // 0..63
    const int ty = threadIdx.y;   // 0..3
    const float* s = src + (size_t)bz * C * N;
    float* d = dst + (size_t)bz * N * C;
    #pragma unroll
    for (int i = 0; i < 16; ++i) {
        int cl = ty + i * 4;
        tile[cl][tx] = s[(size_t)(c0 + cl) * N + n0 + tx];   // coalesced 256B
    }
    __syncthreads();
    #pragma unroll
    for (int i = 0; i < 16; ++i) {
        int nl = ty + i * 4;
        d[(size_t)(n0 + nl) * C + c0 + tx] = tile[tx][nl];   // coalesced 256B
    }
}

// Gather-attention from transposed fp32 K/V (exact math vs reference).
// St/Rt hold batches [b0 .. b0 + gridBatches) contiguously.
__global__ __launch_bounds__(256) void attn_gather(
    const float* __restrict__ Q, const int* __restrict__ Pos,
    const float* __restrict__ St, const float* __restrict__ Rt,
    float* __restrict__ outBuf, float* __restrict__ outM, int b0)
{
    __shared__ float q_s[P_TILE][132];   // Q tile, fp32, padded (conflict-free float4)
    __shared__ float attn_s[P_TILE][17];
    __shared__ int   idx_s[P_TILE][K];
    __shared__ float out_s[P_TILE][132];

    const int tid = threadIdx.x;
    const int bb  = blockIdx.x / BLOCKS_PER_BATCH;   // batch within this launch
    const int b   = b0 + bb;                         // absolute batch
    const int p0  = (blockIdx.x % BLOCKS_PER_BATCH) * P_TILE;

    // ---- phase 0: stage Q tile (coalesced) + compute gather indices ----
    for (int i = tid; i < P_TILE * C; i += 256) {
        int c = i >> 4, pl0 = i & 15;
        q_s[pl0][c] = Q[((size_t)(b * C + c)) * hw + p0 + pl0];
    }
    const int pl = tid >> 4;   // position in tile
    const int kk = tid & 15;   // k index
    const int p  = p0 + pl;
    const int rr = Pos[(((size_t)(b * 2 + 0) * hw) + p) * K + kk];
    const int cc = Pos[(((size_t)(b * 2 + 1) * hw) + p) * K + kk];
    const int idx = rr * W_ + cc;
    idx_s[pl][kk] = idx;
    __syncthreads();

    // ---- phase 1: score = q . K_row, softmax over k (16-lane shuffles) ----
    float score = 0.f;
    {
        const float4* srow = reinterpret_cast<const float4*>(St + ((size_t)bb * HW + idx) * C);
        #pragma unroll
        for (int j = 0; j < 32; ++j) {
            float4 sv = srow[j];                                  // 16B per lane, row 100% line-utilized
            float4 qa = *reinterpret_cast<const float4*>(&q_s[pl][j * 4]);
            score += qa.x * sv.x + qa.y * sv.y + qa.z * sv.z + qa.w * sv.w;
        }
    }
    float mx = score;
    #pragma unroll
    for (int off = 1; off < 16; off <<= 1) mx = fmaxf(mx, __shfl_xor(mx, off));
    float e = __expf(score - mx);
    float ssum = e;
    #pragma unroll
    for (int off = 1; off < 16; off <<= 1) ssum += __shfl_xor(ssum, off);
    const float attn = e / ssum;
    outM[((size_t)b * hw + p) * K + kk] = attn;   // coalesced
    attn_s[pl][kk] = attn;
    __syncthreads();

    // ---- phase 2: out[c] = sum_k attn * V_row[c]; 16 lanes span one 512B V row ----
    {
        const int pl2 = tid >> 4;
        const int cg  = tid & 15;      // 8-channel chunk
        float acc[8];
        #pragma unroll
        for (int i = 0; i < 8; ++i) acc[i] = 0.f;
        #pragma unroll
        for (int k2 = 0; k2 < K; ++k2) {
            const float a = attn_s[pl2][k2];
            const float4* rrow = reinterpret_cast<const float4*>(
                Rt + ((size_t)bb * HW + idx_s[pl2][k2]) * C);
            float4 r0 = rrow[cg * 2];                             // 512B contiguous per 16 lanes
            float4 r1 = rrow[cg * 2 + 1];
            acc[0] += a * r0.x; acc[1] += a * r0.y;
            acc[2] += a * r0.z; acc[3] += a * r0.w;
            acc[4] += a * r1.x; acc[5] += a * r1.y;
            acc[6] += a * r1.z; acc[7] += a * r1.w;
        }
        #pragma unroll
        for (int i = 0; i < 8; ++i) out_s[pl2][cg * 8 + i] = acc[i];
    }
    __syncthreads();
    for (int i = tid; i < P_TILE * C; i += 256) {
        int c = i >> 4, pl3 = i & 15;
        outBuf[((size_t)(b * C + c)) * hw + p0 + pl3] = out_s[pl3][c];   // coalesced
    }
}

// Fallback: direct gather from original (B,C,H,W) layout. Slow but needs no workspace.
__global__ __launch_bounds__(256) void attn_direct(
    const float* __restrict__ Q, const float* __restrict__ S, const float* __restrict__ R,
    const int* __restrict__ Pos, float* __restrict__ outBuf, float* __restrict__ outM)
{
    __shared__ float q_s[P_TILE][132];
    __shared__ float attn_s[P_TILE][17];
    __shared__ int   idx_s[P_TILE][K];
    __shared__ float out_s[P_TILE][132];

    const int tid = threadIdx.x;
    const int b   = blockIdx.x / BLOCKS_PER_BATCH;
    const int p0  = (blockIdx.x % BLOCKS_PER_BATCH) * P_TILE;

    for (int i = tid; i < P_TILE * C; i += 256) {
        int c = i >> 4, pl0 = i & 15;
        q_s[pl0][c] = Q[((size_t)(b * C + c)) * hw + p0 + pl0];
    }
    const int pl = tid >> 4;
    const int kk = tid & 15;
    const int p  = p0 + pl;
    const int rr = Pos[(((size_t)(b * 2 + 0) * hw) + p) * K + kk];
    const int cc = Pos[(((size_t)(b * 2 + 1) * hw) + p) * K + kk];
    const int idx = rr * W_ + cc;
    idx_s[pl][kk] = idx;
    __syncthreads();

    float score = 0.f;
    {
        const float* srow = S + (size_t)b * C * HW + idx;
        for (int c = 0; c < C; ++c) score += q_s[pl][c] * srow[(size_t)c * HW];
    }
    float mx = score;
    #pragma unroll
    for (int off = 1; off < 16; off <<= 1) mx = fmaxf(mx, __shfl_xor(mx, off));
    float e = __expf(score - mx);
    float ssum = e;
    #pragma unroll
    for (int off = 1; off < 16; off <<= 1) ssum += __shfl_xor(ssum, off);
    const float attn = e / ssum;
    outM[((size_t)b * hw + p) * K + kk] = attn;
    attn_s[pl][kk] = attn;
    __syncthreads();

    {
        const int pl2 = tid >> 4;
        const int cg  = tid & 15;
        float acc[8];
        #pragma unroll
        for (int i = 0; i < 8; ++i) acc[i] = 0.f;
        for (int k2 = 0; k2 < K; ++k2) {
            const float a = attn_s[pl2][k2];
            const float* rw = R + (size_t)b * C * HW + idx_s[pl2][k2];
            #pragma unroll
            for (int i = 0; i < 8; ++i) acc[i] += a * rw[(size_t)(cg * 8 + i) * HW];
        }
        #pragma unroll
        for (int i = 0; i < 8; ++i) out_s[pl2][cg * 8 + i] = acc[i];
    }
    __syncthreads();
    for (int i = tid; i < P_TILE * C; i += 256) {
        int c = i >> 4, pl3 = i & 15;
        outBuf[((size_t)(b * C + c)) * hw + p0 + pl3] = out_s[pl3][c];
    }
}

extern "C" void kernel_launch(void* const* d_in, const int* in_sizes, int n_in,
                              void* d_out, int out_size, void* d_ws, size_t ws_size,
                              hipStream_t stream)
{
    (void)in_sizes; (void)n_in; (void)out_size;
    const float* Q  = (const float*)d_in[0];
    const float* S  = (const float*)d_in[1];
    const float* R  = (const float*)d_in[2];
    const int*  Pos = (const int*)d_in[3];
    float* outBuf = (float*)d_out;
    float* outM   = outBuf + (size_t)B * C * hw;   // buffer is B*Cv*h*w elements

    const size_t perBatchElems = (size_t)HW * C;                              // 8,388,608
    const size_t fullBytes     = 2 * (size_t)B * perBatchElems * sizeof(float); // 256 MiB
    const size_t perBatchBytes = 2 * perBatchElems * sizeof(float);           // 64 MiB

    dim3 tb(64, 4);
    if (ws_size >= fullBytes) {
        // transpose all batches once, then one big compute launch
        float* St = (float*)d_ws;
        float* Rt = St + (size_t)B * perBatchElems;
        dim3 tg(HW / 64, C / 64, B);
        transpose_f32<<<tg, tb, 0, stream>>>(S, St, HW);
        transpose_f32<<<tg, tb, 0, stream>>>(R, Rt, HW);
        attn_gather<<<dim3(B * BLOCKS_PER_BATCH), 256, 0, stream>>>(
            Q, Pos, St, Rt, outBuf, outM, 0);
    } else if (ws_size >= perBatchBytes) {
        // per-batch transpose + compute, workspace reused
        float* St = (float*)d_ws;
        float* Rt = St + perBatchElems;
        dim3 tg(HW / 64, C / 64, 1);
        for (int b = 0; b < B; ++b) {
            transpose_f32<<<tg, tb, 0, stream>>>(S + (size_t)b * C * HW, St, HW);
            transpose_f32<<<tg, tb, 0, stream>>>(R + (size_t)b * C * HW, Rt, HW);
            attn_gather<<<dim3(BLOCKS_PER_BATCH), 256, 0, stream>>>(
                Q, Pos, St, Rt, outBuf, outM, b);
        }
    } else {
        // no usable workspace: direct (uncoalesced) gather
        attn_direct<<<dim3(B * BLOCKS_PER_BATCH), 256, 0, stream>>>(
            Q, S, R, Pos, outBuf, outM);
    }
}